// Round 15
// baseline (61.264 us; speedup 1.0000x reference)
//
#include <hip/hip_runtime.h>

#define IMGW 28
#define OUTW 26
#define FLAT (OUTW * OUTW)
#define NCLS 10
#define WROW 28   // padded col stride inside wL rows; class stride 112B = 16B-mult

// lane = image (64 imgs per block-pair). Each 64-image group is covered by TWO
// half-blocks (h = bid&1): h=0 -> output rows 0..12, h=1 -> rows 13..25. Grid
// 1024 -> 4 blocks/CU -> 32 waves/CU residency, which requires VGPR<=64:
// 3-slot rolling 6-float row buffers (13 bodies = 4x3 + tail, static slots),
// f4+f2 loads. Waves 0..6 take 4-wide output-col strips (wave6: cols 24,25,
// one f4 load of cols 24..27 -> in-bounds). Max loaded input row = s+14 = 27.
// FC weights for this half's 13 rows live in LDS (14.6KB) read at wave-uniform
// b128 addresses; the same buffer is reused (post-barrier) for partial logits.
// The two halves combine via 2-addend f32 atomicAdd (commutative -> replay-
// deterministic) onto memset-zeroed out; bias added by half 0 only.
// This round's experiment: 2x resident waves at constant per-CU work -- if
// latency-bound, dur drops toward ~25us; if L1 line-walk-throughput-bound,
// dur stays ~40us and the next lever is bytes/instruction.
__global__ __launch_bounds__(512, 4) void fused_conv_fc_kernel(
    const float* __restrict__ x,       // [B, 784]
    const float* __restrict__ conv_w,  // [3,3]
    const float* __restrict__ fc_w,    // [10, 676]
    const float* __restrict__ fc_b,    // [10]
    float* __restrict__ out)           // [B, 10] (pre-zeroed)
{
    __shared__ float shbuf[3840];   // 15360B: wL[13][10][28] (3640) then part[6][64][10]

    const int tid  = threadIdx.x;
    const int lane = tid & 63;
    const int wid  = __builtin_amdgcn_readfirstlane(tid >> 6);
    const int h    = blockIdx.x & 1;          // row half
    const int img  = (blockIdx.x >> 1) * 64 + lane;
    const int s    = h * 13;                  // first output row of this half

    const float* ip = x + (size_t)img * (IMGW * IMGW);

    // stage this half's fc_w rows: wL[(rl*10+c)*28+cc] = fc_w[c*676+(s+rl)*26+cc]
    for (int i = tid; i < 13 * NCLS * WROW; i += 512) {
        int rl  = i / (NCLS * WROW);
        int rem = i - rl * (NCLS * WROW);
        int c   = rem / WROW;
        int cc  = rem - c * WROW;
        shbuf[i] = (cc < OUTW) ? fc_w[c * FLAT + (s + rl) * OUTW + cc] : 0.f;
    }

    const float cw0 = conv_w[0], cw1 = conv_w[1], cw2 = conv_w[2];
    const float cw3 = conv_w[3], cw4 = conv_w[4], cw5 = conv_w[5];
    const float cw6 = conv_w[6], cw7 = conv_w[7], cw8 = conv_w[8];

    __syncthreads();

    float acc[NCLS];
#pragma unroll
    for (int c = 0; c < NCLS; ++c) acc[c] = 0.f;

    if (wid < 7) {
        const int  c0   = (wid == 6) ? 24 : 4 * wid;
        const int  wv   = (wid == 6) ? 2  : 4;
        const bool full = (wid != 6);

        __attribute__((aligned(16))) float b0[6], b1[6], b2[6];

#define LOADR(BUF, RR) do {                                            \
        const float* _p = ip + (RR) * IMGW + c0;                       \
        *(float4*)&BUF[0] = *(const float4*)_p;                        \
        if (full) *(float2*)&BUF[4] = *(const float2*)(_p + 4);        \
    } while (0)

        if (!full) { b0[4]=b0[5]=b1[4]=b1[5]=b2[4]=b2[5]=0.f; }

        LOADR(b0, s + 0); LOADR(b1, s + 1); LOADR(b2, s + 2);

        // body: conv h[4] from slots A,B,C; prefetch row RL into L (used next
        // body); FC via 10 wave-uniform b128 reads of this half's weight row.
#define BODY(A, B, C, L, RL, RL_OK, RLOC) do {                         \
        float hh[4];                                                   \
        _Pragma("unroll")                                              \
        for (int j = 0; j < 4; ++j) {                                  \
            float t = A[j]   * cw0 + A[j+1] * cw1 + A[j+2] * cw2       \
                    + B[j]   * cw3 + B[j+1] * cw4 + B[j+2] * cw5       \
                    + C[j]   * cw6 + C[j+1] * cw7 + C[j+2] * cw8;      \
            t = fmaxf(t, 0.f);                                         \
            hh[j] = (j >= wv) ? 0.f : t;                               \
        }                                                              \
        if (RL_OK) LOADR(L, RL);                                       \
        const float* _w = &shbuf[(RLOC) * (NCLS * WROW) + c0];         \
        _Pragma("unroll")                                              \
        for (int c = 0; c < NCLS; ++c) {                               \
            float4 wf = *(const float4*)&_w[c * WROW];                 \
            acc[c] = fmaf(hh[0], wf.x, acc[c]);                        \
            acc[c] = fmaf(hh[1], wf.y, acc[c]);                        \
            acc[c] = fmaf(hh[2], wf.z, acc[c]);                        \
            acc[c] = fmaf(hh[3], wf.w, acc[c]);                        \
        }                                                              \
    } while (0)

        int rl = 0;                // local output row (weights index)
#pragma unroll 1
        for (int t4 = 0; t4 < 4; ++t4) {   // 12 bodies; loads reach s+14 (<=27)
            BODY(b0, b1, b2, b0, s + rl + 3, true, rl + 0);
            BODY(b1, b2, b0, b1, s + rl + 4, true, rl + 1);
            BODY(b2, b0, b1, b2, s + rl + 5, true, rl + 2);
            rl += 3;
        }
        BODY(b0, b1, b2, b0, 0, false, 12);   // tail: rows s+12..s+14, no load
#undef LOADR
#undef BODY
    }

    __syncthreads();   // all waves done reading wL -> safe to reuse as part[]
    if (wid >= 1 && wid < 7) {
#pragma unroll
        for (int c = 0; c < NCLS; ++c)
            shbuf[((wid - 1) * 64 + lane) * NCLS + c] = acc[c];
    }
    __syncthreads();
    if (wid == 0) {
        float* o = out + (size_t)img * NCLS;
#pragma unroll
        for (int c = 0; c < NCLS; ++c) {
            float t = acc[c];
#pragma unroll
            for (int w = 0; w < 6; ++w) t += shbuf[(w * 64 + lane) * NCLS + c];
            if (h == 0) t += fc_b[c];
            atomicAdd(o + c, t);   // exactly 2 addends/location -> deterministic
        }
    }
}

extern "C" void kernel_launch(void* const* d_in, const int* in_sizes, int n_in,
                              void* d_out, int out_size, void* d_ws, size_t ws_size,
                              hipStream_t stream) {
    const float* x      = (const float*)d_in[0];
    const float* conv_w = (const float*)d_in[1];
    const float* fc_w   = (const float*)d_in[2];
    const float* fc_b   = (const float*)d_in[3];
    float* out = (float*)d_out;

    const int nimg   = in_sizes[0] / (IMGW * IMGW);  // 32768
    const int blocks = (nimg / 64) * 2;              // 1024 half-blocks

    hipMemsetAsync(out, 0, (size_t)out_size * sizeof(float), stream);
    hipLaunchKernelGGL(fused_conv_fc_kernel, dim3(blocks), dim3(512), 0, stream,
                       x, conv_w, fc_w, fc_b, out);
}